// Round 11
// baseline (409.788 us; speedup 1.0000x reference)
//
#include <hip/hip_runtime.h>

#define NN 50000
#define NE 800000
#define NH 64
#define NG 500
#define NPAD 50176   // 196*256
#define NBKT 782     // ceil(NN/64) 64-node buckets
#define CAP 1536     // padded bucket capacity (max bucket deg ~1130; 4.5+ sigma margin)

// fp32 -> bf16 round-to-nearest-even
__device__ __forceinline__ unsigned short f2bf(float f) {
  unsigned x = __float_as_uint(f);
  unsigned r = ((x >> 16) & 1u) + 0x7fffu;
  return (unsigned short)((x + r) >> 16);
}
__device__ __forceinline__ float bf2f(unsigned short u) {
  return __uint_as_float(((unsigned)u) << 16);
}

// ---------------- binning into padded buckets: colp[b*CAP + r] ----------------
// word = (src<<6) | (dst&63). LDS histogram -> one bulk reserve per (block,bucket)
// via atomicAdd(bcur[b]) -> rank-addressed line-dense writes. No scan needed.

__global__ __launch_bounds__(256) void k_bin(const int* __restrict__ src, const int* __restrict__ dst,
                                             int* __restrict__ bcur, int* __restrict__ colp) {
  __shared__ int hist[NBKT];
  __shared__ int gbase[NBKT];
  int t = threadIdx.x;
  for (int b = t; b < NBKT; b += 256) hist[b] = 0;
  __syncthreads();
  int e0 = blockIdx.x * 8192;
#pragma unroll
  for (int i = 0; i < 32; i++) {
    int e = e0 + i * 256 + t;
    if (e < NE) atomicAdd(&hist[dst[e] >> 6], 1);
  }
  __syncthreads();
  for (int b = t; b < NBKT; b += 256) {
    int c = hist[b];
    gbase[b] = c ? atomicAdd(&bcur[b], c) : 0;
    hist[b] = 0;  // reuse as rank counter
  }
  __syncthreads();
#pragma unroll
  for (int i = 0; i < 32; i++) {
    int e = e0 + i * 256 + t;
    if (e < NE) {
      int s = src[e], d = dst[e];
      int b = d >> 6;
      int r = atomicAdd(&hist[b], 1);
      colp[b * CAP + gbase[b] + r] = (s << 6) | (d & 63);
    }
  }
}

// ---------------- bucket-local sort to padded CSR + dinv/rowst/rowen (+ gptr folded) ----------------

__global__ __launch_bounds__(256) void k_csr(const int* __restrict__ bcur, const int* __restrict__ colp,
                                             int* __restrict__ cols, float* __restrict__ dinv,
                                             int* __restrict__ rowst, int* __restrict__ rowen,
                                             const int* __restrict__ batch, int* __restrict__ gptr) {
  __shared__ int hist[64];
  __shared__ int excl[65];
  int t = threadIdx.x;
  int b = blockIdx.x;

  // folded gptr: graph segment pointers from sorted batch (independent work)
  int tid = b * 256 + t;
  if (tid < NN) {
    int bi = batch[tid];
    int bp = (tid > 0) ? batch[tid - 1] : -1;
    for (int g = bp + 1; g <= bi; g++) gptr[g] = tid;
    if (tid == NN - 1) {
      for (int g = bi + 1; g <= NG; g++) gptr[g] = NN;
    }
  }

  int base = b * CAP;
  int cnt = bcur[b];
  if (t < 64) hist[t] = 0;
  __syncthreads();
  for (int e = t; e < cnt; e += 256) atomicAdd(&hist[colp[base + e] & 63], 1);
  __syncthreads();
  if (t == 0) {
    int run = 0;
#pragma unroll
    for (int i = 0; i < 64; i++) { excl[i] = run; run += hist[i]; }
    excl[64] = run;
  }
  __syncthreads();
  if (t < 64) {
    int n = b * 64 + t;
    rowst[n] = base + excl[t];
    rowen[n] = base + excl[t + 1];
    if (n < NN) dinv[n] = rsqrtf((float)(hist[t] + 1));  // +1 self-loop
    hist[t] = 0;  // reuse as cursor
  }
  __syncthreads();
  for (int e = t; e < cnt; e += 256) {
    int w = colp[base + e];
    int d = w & 63;
    int r = atomicAdd(&hist[d], 1);
    cols[base + excl[d] + r] = w >> 6;
  }
}

// ---------------- encoder: X0 = [x|pos] @ enc_W + enc_b ----------------

__global__ __launch_bounds__(256) void k_encoder(const float* __restrict__ x, const float* __restrict__ pos,
                                                 const float* __restrict__ W, const float* __restrict__ b,
                                                 float* __restrict__ X0) {
  __shared__ float Ws[16 * 64];
  __shared__ float bs[64];
  int t = threadIdx.x;
  for (int i = t; i < 1024; i += 256) Ws[i] = W[i];
  if (t < 64) bs[t] = b[t];
  __syncthreads();
  int n = blockIdx.x * 4 + (t >> 6);
  int h = t & 63;
  if (n >= NN) return;
  float acc = bs[h];
#pragma unroll
  for (int f = 0; f < 14; f++) acc += x[n * 14 + f] * Ws[f * 64 + h];
  acc += pos[n * 2 + 0] * Ws[14 * 64 + h];
  acc += pos[n * 2 + 1] * Ws[15 * 64 + h];
  X0[n * 64 + h] = acc;
}

// ---------------- fused dual GEMM + epilogue (64-node tile, 48 KB LDS -> 3 blocks/CU) ----------------
// mode 0: X = Xin (encoder output). mode 1: X = relu(Xin + dinv[n]*bf2f(gsum[n])).
// hWs = dinv[n] * (X @ conv_W) is quantized per-row to int8: q = rint(127*hWs/rowmax),
// scl[n] = rowmax/127 (64 B rows -> 2 rows per 128 B line; 3.2 MB working set fits L2).
// agg = X @ res_W + res_b + conv_b + dinv[n]*hWs[n]   (self-loop in fp32)

__global__ __launch_bounds__(256) void k_gemm_dual(const float* __restrict__ Xin,
                                                   const unsigned short* __restrict__ gsum,
                                                   const float* __restrict__ Wc, const float* __restrict__ Wr,
                                                   const float* __restrict__ cb, const float* __restrict__ rb,
                                                   const float* __restrict__ dinv,
                                                   signed char* __restrict__ hWq, float* __restrict__ scl,
                                                   float* __restrict__ agg, int mode) {
  __shared__ float Xs[64 * 64];
  __shared__ float Wcs[64 * 64];
  __shared__ float Wrs[64 * 64];
  int t = threadIdx.x;
#pragma unroll
  for (int j = 0; j < 4; j++) {
    ((float4*)Wcs)[t + j * 256] = ((const float4*)Wc)[t + j * 256];
    ((float4*)Wrs)[t + j * 256] = ((const float4*)Wr)[t + j * 256];
  }
  int n0 = blockIdx.x * 64;
#pragma unroll
  for (int i = 0; i < 4; i++) {
    int idx = t + i * 256;        // float4 index in 64x64 tile (1024 total)
    int n = idx >> 4;             // 16 float4 per row
    int kg = (idx & 15) << 2;
    float4 v = make_float4(0.f, 0.f, 0.f, 0.f);
    int gn = n0 + n;
    if (gn < NN) {
      v = *(const float4*)(Xin + gn * 64 + kg);
      if (mode) {
        ushort4 g = *(const ushort4*)(gsum + gn * 64 + kg);
        float dvn = dinv[gn];
        v.x = fmaxf(v.x + dvn * bf2f(g.x), 0.f);
        v.y = fmaxf(v.y + dvn * bf2f(g.y), 0.f);
        v.z = fmaxf(v.z + dvn * bf2f(g.z), 0.f);
        v.w = fmaxf(v.w + dvn * bf2f(g.w), 0.f);
      }
    }
    int sw = ((n >> 2) & 7) << 2;  // float4-preserving bank swizzle
    *(float4*)(Xs + n * 64 + (kg ^ sw)) = v;
  }
  __syncthreads();

  int hg = (t & 15) << 2;   // h0 (4 consecutive h)
  int ng = t >> 4;          // node group (16 groups x 4 nodes)
  int nb = ng << 2;
  int swz = (ng & 7) << 2;  // rows nb..nb+3 share row>>2 == ng

  float aC[4][4] = {};
  float aR[4][4] = {};
#pragma unroll 4
  for (int k = 0; k < 64; k++) {
    float4 wc = *(const float4*)(Wcs + k * 64 + hg);
    float4 wr = *(const float4*)(Wrs + k * 64 + hg);
    int kk = k ^ swz;
#pragma unroll
    for (int i = 0; i < 4; i++) {
      float xv = Xs[(nb + i) * 64 + kk];
      aC[i][0] += xv * wc.x; aC[i][1] += xv * wc.y; aC[i][2] += xv * wc.z; aC[i][3] += xv * wc.w;
      aR[i][0] += xv * wr.x; aR[i][1] += xv * wr.y; aR[i][2] += xv * wr.z; aR[i][3] += xv * wr.w;
    }
  }

  float4 cbv = *(const float4*)(cb + hg);
  float4 rbv = *(const float4*)(rb + hg);
#pragma unroll
  for (int i = 0; i < 4; i++) {
    int n = n0 + nb + i;
    if (n < NN) {  // uniform across the 16-lane row group (same n) -> shuffles safe
      float dv = dinv[n];
      float4 hv;
      hv.x = dv * aC[i][0]; hv.y = dv * aC[i][1]; hv.z = dv * aC[i][2]; hv.w = dv * aC[i][3];
      // row max over the 16 threads holding this node's 64 h values
      float m = fmaxf(fmaxf(fabsf(hv.x), fabsf(hv.y)), fmaxf(fabsf(hv.z), fabsf(hv.w)));
      m = fmaxf(m, __shfl_xor(m, 1, 64));
      m = fmaxf(m, __shfl_xor(m, 2, 64));
      m = fmaxf(m, __shfl_xor(m, 4, 64));
      m = fmaxf(m, __shfl_xor(m, 8, 64));
      float inv = (m > 0.f) ? 127.f / m : 0.f;
      int qx = (int)rintf(hv.x * inv);
      int qy = (int)rintf(hv.y * inv);
      int qz = (int)rintf(hv.z * inv);
      int qw = (int)rintf(hv.w * inv);
      int packed = (qx & 255) | ((qy & 255) << 8) | ((qz & 255) << 16) | (qw << 24);
      *(int*)(hWq + (size_t)n * 64 + hg) = packed;
      if ((t & 15) == 0) scl[n] = m * (1.f / 127.f);
      float4 av;
      av.x = aR[i][0] + rbv.x + cbv.x + dv * hv.x;
      av.y = aR[i][1] + rbv.y + cbv.y + dv * hv.y;
      av.z = aR[i][2] + rbv.z + cbv.z + dv * hv.z;
      av.w = aR[i][3] + rbv.w + cbv.w + dv * hv.w;
      *(float4*)(agg + n * 64 + hg) = av;
    }
  }
}

// ---------------- CSR gather: gsum[n] = bf16( sum_e scl[s]*q8[s] ) ----------------
// One 64-lane wave per dst node; int8 row = 64 B (2 rows/line -> miss volume halves,
// 3.2 MB working set L2-resident). ILP-16. scl lookups forced scalar (readfirstlane
// -> s_load through the scalar cache). Last layer skips gsum and fuses decode.

__global__ __launch_bounds__(256) void k_gather(const int* __restrict__ rowst, const int* __restrict__ rowen,
                                                const int* __restrict__ cols,
                                                const signed char* __restrict__ hWq,
                                                const float* __restrict__ scl,
                                                unsigned short* __restrict__ gsum,
                                                const float* __restrict__ agg, const float* __restrict__ dinv,
                                                const float* __restrict__ decW, float* __restrict__ Xo,
                                                int last) {
  int lane = threadIdx.x & 63;
  int n = __builtin_amdgcn_readfirstlane(blockIdx.x * 4 + (threadIdx.x >> 6));
  int st = rowst[n];
  int en = rowen[n];
  int deg = en - st;
  float acc = 0.f;
  for (int base = 0; base < deg; base += 64) {
    int cnt = deg - base;
    if (cnt > 64) cnt = 64;
    int li = lane < cnt ? lane : cnt - 1;
    int colv = cols[st + base + li];  // one coalesced row-load of up to 64 indices
    for (int j = 0; j < cnt; j += 16) {
      int i0 = j + 0, i1 = j + 1, i2 = j + 2, i3 = j + 3;
      int i4 = j + 4, i5 = j + 5, i6 = j + 6, i7 = j + 7;
      int i8 = j + 8, i9 = j + 9, iA = j + 10, iB = j + 11;
      int iC = j + 12, iD = j + 13, iE = j + 14, iF = j + 15;
      int s0 = __builtin_amdgcn_readfirstlane(__shfl(colv, i0, 64));
      int s1 = __builtin_amdgcn_readfirstlane(__shfl(colv, i1 < cnt ? i1 : j, 64));
      int s2 = __builtin_amdgcn_readfirstlane(__shfl(colv, i2 < cnt ? i2 : j, 64));
      int s3 = __builtin_amdgcn_readfirstlane(__shfl(colv, i3 < cnt ? i3 : j, 64));
      int s4 = __builtin_amdgcn_readfirstlane(__shfl(colv, i4 < cnt ? i4 : j, 64));
      int s5 = __builtin_amdgcn_readfirstlane(__shfl(colv, i5 < cnt ? i5 : j, 64));
      int s6 = __builtin_amdgcn_readfirstlane(__shfl(colv, i6 < cnt ? i6 : j, 64));
      int s7 = __builtin_amdgcn_readfirstlane(__shfl(colv, i7 < cnt ? i7 : j, 64));
      int s8 = __builtin_amdgcn_readfirstlane(__shfl(colv, i8 < cnt ? i8 : j, 64));
      int s9 = __builtin_amdgcn_readfirstlane(__shfl(colv, i9 < cnt ? i9 : j, 64));
      int sA = __builtin_amdgcn_readfirstlane(__shfl(colv, iA < cnt ? iA : j, 64));
      int sB = __builtin_amdgcn_readfirstlane(__shfl(colv, iB < cnt ? iB : j, 64));
      int sC = __builtin_amdgcn_readfirstlane(__shfl(colv, iC < cnt ? iC : j, 64));
      int sD = __builtin_amdgcn_readfirstlane(__shfl(colv, iD < cnt ? iD : j, 64));
      int sE = __builtin_amdgcn_readfirstlane(__shfl(colv, iE < cnt ? iE : j, 64));
      int sF = __builtin_amdgcn_readfirstlane(__shfl(colv, iF < cnt ? iF : j, 64));
      float w0 = scl[s0], w1 = scl[s1], w2 = scl[s2], w3 = scl[s3];
      float w4 = scl[s4], w5 = scl[s5], w6 = scl[s6], w7 = scl[s7];
      float w8 = scl[s8], w9 = scl[s9], wA = scl[sA], wB = scl[sB];
      float wC = scl[sC], wD = scl[sD], wE = scl[sE], wF = scl[sF];
      float v0 = (float)hWq[(size_t)s0 * 64 + lane];
      float v1 = (float)hWq[(size_t)s1 * 64 + lane];
      float v2 = (float)hWq[(size_t)s2 * 64 + lane];
      float v3 = (float)hWq[(size_t)s3 * 64 + lane];
      float v4 = (float)hWq[(size_t)s4 * 64 + lane];
      float v5 = (float)hWq[(size_t)s5 * 64 + lane];
      float v6 = (float)hWq[(size_t)s6 * 64 + lane];
      float v7 = (float)hWq[(size_t)s7 * 64 + lane];
      float v8 = (float)hWq[(size_t)s8 * 64 + lane];
      float v9 = (float)hWq[(size_t)s9 * 64 + lane];
      float vA = (float)hWq[(size_t)sA * 64 + lane];
      float vB = (float)hWq[(size_t)sB * 64 + lane];
      float vC = (float)hWq[(size_t)sC * 64 + lane];
      float vD = (float)hWq[(size_t)sD * 64 + lane];
      float vE = (float)hWq[(size_t)sE * 64 + lane];
      float vF = (float)hWq[(size_t)sF * 64 + lane];
      acc += w0 * v0;
      acc += (i1 < cnt) ? w1 * v1 : 0.f;
      acc += (i2 < cnt) ? w2 * v2 : 0.f;
      acc += (i3 < cnt) ? w3 * v3 : 0.f;
      acc += (i4 < cnt) ? w4 * v4 : 0.f;
      acc += (i5 < cnt) ? w5 * v5 : 0.f;
      acc += (i6 < cnt) ? w6 * v6 : 0.f;
      acc += (i7 < cnt) ? w7 * v7 : 0.f;
      acc += (i8 < cnt) ? w8 * v8 : 0.f;
      acc += (i9 < cnt) ? w9 * v9 : 0.f;
      acc += (iA < cnt) ? wA * vA : 0.f;
      acc += (iB < cnt) ? wB * vB : 0.f;
      acc += (iC < cnt) ? wC * vC : 0.f;
      acc += (iD < cnt) ? wD * vD : 0.f;
      acc += (iE < cnt) ? wE * vE : 0.f;
      acc += (iF < cnt) ? wF * vF : 0.f;
    }
  }
  if (!last) {
    gsum[n * 64 + lane] = f2bf(acc);
  } else {
    float xf = agg[n * 64 + lane] + dinv[n] * acc;  // X_final pre-relu (fp32 acc)
    float v = fmaxf(xf, 0.f) * decW[lane];
#pragma unroll
    for (int off = 32; off > 0; off >>= 1) v += __shfl_down(v, off, 64);
    if (lane == 0) Xo[n] = v;
  }
}

// ---------------- graph pooling: out[g] = sum Xo[gptr[g]:gptr[g+1]] + cnt*decb ----------------

__global__ __launch_bounds__(256) void k_pool(const float* __restrict__ Xo, const int* __restrict__ gptr,
                                              const float* __restrict__ decb, float* __restrict__ out) {
  __shared__ float part[4];
  int g = blockIdx.x;
  int t = threadIdx.x;
  int st = gptr[g], en = gptr[g + 1];
  float v = 0.f;
  for (int i = st + t; i < en; i += 256) v += Xo[i];
#pragma unroll
  for (int off = 32; off > 0; off >>= 1) v += __shfl_down(v, off, 64);
  if ((t & 63) == 0) part[t >> 6] = v;
  __syncthreads();
  if (t == 0) out[g] = part[0] + part[1] + part[2] + part[3] + (float)(en - st) * decb[0];
}

// ---------------- launch ----------------

extern "C" void kernel_launch(void* const* d_in, const int* in_sizes, int n_in,
                              void* d_out, int out_size, void* d_ws, size_t ws_size,
                              hipStream_t stream) {
  (void)in_sizes; (void)n_in; (void)out_size; (void)ws_size;
  const float* x     = (const float*)d_in[0];
  const float* pos   = (const float*)d_in[1];
  const int*   ei    = (const int*)d_in[2];
  const int*   batch = (const int*)d_in[3];
  const float* encW  = (const float*)d_in[4];
  const float* encb  = (const float*)d_in[5];
  const float* convW = (const float*)d_in[6];
  const float* convb = (const float*)d_in[7];
  const float* resW  = (const float*)d_in[8];
  const float* resb  = (const float*)d_in[9];
  const float* decW  = (const float*)d_in[10];
  const float* decb  = (const float*)d_in[11];
  float* out = (float*)d_out;

  const int* src = ei;       // edge_index[0]
  const int* dst = ei + NE;  // edge_index[1]

  // workspace layout (4-byte elems)
  float*          ws     = (float*)d_ws;
  float*          dinv   = ws;                          // [NPAD]
  int*            rowst  = (int*)(ws + NPAD);           // [NPAD]
  int*            rowen  = (int*)(ws + 2 * NPAD);       // [NPAD]
  int*            bcur   = (int*)(ws + 3 * NPAD);       // [1024]
  int*            gptr   = bcur + 1024;                 // [NG+1]
  float*          Xo     = (float*)(gptr + 512);        // [NPAD]
  float*          scl    = Xo + NPAD;                   // [NPAD] int8 row scales
  int*            colp   = (int*)(scl + NPAD);          // [NBKT*CAP] packed (src<<6)|dstLow
  int*            cols   = colp + NBKT * CAP;           // [NBKT*CAP] sorted src
  signed char*    hWq    = (signed char*)(cols + NBKT * CAP);         // [NPAD*64] int8
  unsigned short* gsum   = (unsigned short*)(hWq + (size_t)NPAD * 64);  // [NPAD*64] bf16
  float*          bufA   = (float*)(gsum + (size_t)NPAD * 64);        // [NN*NH]
  float*          bufB   = bufA + NN * NH;

  hipMemsetAsync(bcur, 0, 1024 * sizeof(int), stream);

  k_bin<<<(NE + 8191) / 8192, 256, 0, stream>>>(src, dst, bcur, colp);
  k_csr<<<NBKT, 256, 0, stream>>>(bcur, colp, cols, dinv, rowst, rowen, batch, gptr);

  k_encoder<<<(NN + 3) / 4, 256, 0, stream>>>(x, pos, encW, encb, bufA);

  float* aggIn = bufA;   // X0 for l=0; thereafter agg_{l-1}
  float* aggOut = bufB;
  for (int l = 0; l < 5; l++) {
    int last = (l == 4) ? 1 : 0;
    k_gemm_dual<<<NBKT, 256, 0, stream>>>(aggIn, gsum, convW, resW, convb, resb, dinv,
                                          hWq, scl, aggOut, l > 0 ? 1 : 0);
    k_gather<<<NN / 4, 256, 0, stream>>>(rowst, rowen, cols, hWq, scl, gsum,
                                         aggOut, dinv, decW, Xo, last);
    float* tmp = aggIn; aggIn = aggOut; aggOut = tmp;
  }
  k_pool<<<NG, 256, 0, stream>>>(Xo, gptr, decb, out);
}

// Round 12
// 361.232 us; speedup vs baseline: 1.1344x; 1.1344x over previous
//
#include <hip/hip_runtime.h>

#define NN 50000
#define NE 800000
#define NH 64
#define NG 500
#define NPAD 50176   // 196*256
#define NBKT 782     // ceil(NN/64) 64-node buckets
#define CAP 1536     // padded bucket capacity (max bucket deg ~1130; 4.5+ sigma margin)

// fp32 -> bf16 round-to-nearest-even
__device__ __forceinline__ unsigned short f2bf(float f) {
  unsigned x = __float_as_uint(f);
  unsigned r = ((x >> 16) & 1u) + 0x7fffu;
  return (unsigned short)((x + r) >> 16);
}
__device__ __forceinline__ float bf2f(unsigned short u) {
  return __uint_as_float(((unsigned)u) << 16);
}

// ---------------- binning into padded buckets: colp[b*CAP + r] ----------------

__global__ __launch_bounds__(256) void k_bin(const int* __restrict__ src, const int* __restrict__ dst,
                                             int* __restrict__ bcur, int* __restrict__ colp) {
  __shared__ int hist[NBKT];
  __shared__ int gbase[NBKT];
  int t = threadIdx.x;
  for (int b = t; b < NBKT; b += 256) hist[b] = 0;
  __syncthreads();
  int e0 = blockIdx.x * 8192;
#pragma unroll
  for (int i = 0; i < 32; i++) {
    int e = e0 + i * 256 + t;
    if (e < NE) atomicAdd(&hist[dst[e] >> 6], 1);
  }
  __syncthreads();
  for (int b = t; b < NBKT; b += 256) {
    int c = hist[b];
    gbase[b] = c ? atomicAdd(&bcur[b], c) : 0;
    hist[b] = 0;  // reuse as rank counter
  }
  __syncthreads();
#pragma unroll
  for (int i = 0; i < 32; i++) {
    int e = e0 + i * 256 + t;
    if (e < NE) {
      int s = src[e], d = dst[e];
      int b = d >> 6;
      int r = atomicAdd(&hist[b], 1);
      colp[b * CAP + gbase[b] + r] = (s << 6) | (d & 63);
    }
  }
}

// ---------------- bucket-local sort to padded CSR + dinv/rowst/rowen (+ gptr folded) ----------------

__global__ __launch_bounds__(256) void k_csr(const int* __restrict__ bcur, const int* __restrict__ colp,
                                             int* __restrict__ cols, float* __restrict__ dinv,
                                             int* __restrict__ rowst, int* __restrict__ rowen,
                                             const int* __restrict__ batch, int* __restrict__ gptr) {
  __shared__ int hist[64];
  __shared__ int excl[65];
  int t = threadIdx.x;
  int b = blockIdx.x;

  // folded gptr: graph segment pointers from sorted batch (independent work)
  int tid = b * 256 + t;
  if (tid < NN) {
    int bi = batch[tid];
    int bp = (tid > 0) ? batch[tid - 1] : -1;
    for (int g = bp + 1; g <= bi; g++) gptr[g] = tid;
    if (tid == NN - 1) {
      for (int g = bi + 1; g <= NG; g++) gptr[g] = NN;
    }
  }

  int base = b * CAP;
  int cnt = bcur[b];
  if (t < 64) hist[t] = 0;
  __syncthreads();
  for (int e = t; e < cnt; e += 256) atomicAdd(&hist[colp[base + e] & 63], 1);
  __syncthreads();
  if (t == 0) {
    int run = 0;
#pragma unroll
    for (int i = 0; i < 64; i++) { excl[i] = run; run += hist[i]; }
    excl[64] = run;
  }
  __syncthreads();
  if (t < 64) {
    int n = b * 64 + t;
    rowst[n] = base + excl[t];
    rowen[n] = base + excl[t + 1];
    if (n < NN) dinv[n] = rsqrtf((float)(hist[t] + 1));  // +1 self-loop
    hist[t] = 0;  // reuse as cursor
  }
  __syncthreads();
  for (int e = t; e < cnt; e += 256) {
    int w = colp[base + e];
    int d = w & 63;
    int r = atomicAdd(&hist[d], 1);
    cols[base + excl[d] + r] = w >> 6;
  }
}

// ---------------- encoder: X0 = [x|pos] @ enc_W + enc_b ----------------

__global__ __launch_bounds__(256) void k_encoder(const float* __restrict__ x, const float* __restrict__ pos,
                                                 const float* __restrict__ W, const float* __restrict__ b,
                                                 float* __restrict__ X0) {
  __shared__ float Ws[16 * 64];
  __shared__ float bs[64];
  int t = threadIdx.x;
  for (int i = t; i < 1024; i += 256) Ws[i] = W[i];
  if (t < 64) bs[t] = b[t];
  __syncthreads();
  int n = blockIdx.x * 4 + (t >> 6);
  int h = t & 63;
  if (n >= NN) return;
  float acc = bs[h];
#pragma unroll
  for (int f = 0; f < 14; f++) acc += x[n * 14 + f] * Ws[f * 64 + h];
  acc += pos[n * 2 + 0] * Ws[14 * 64 + h];
  acc += pos[n * 2 + 1] * Ws[15 * 64 + h];
  X0[n * 64 + h] = acc;
}

// ---------------- fused dual GEMM + epilogue (64-node tile, 48 KB LDS -> 3 blocks/CU) ----------------
// mode 0: X = Xin (encoder output). mode 1: X = relu(Xin + dinv[n]*bf2f(gsum[n])).
// hWs = dinv[n] * (X @ conv_W) quantized per-row to int8: q = rint(127*hWs/rowmax),
// scl[n] = rowmax/127. 64 B rows -> 2 rows per 128 B line, 3.2 MB working set (fits L2).
// agg = X @ res_W + res_b + conv_b + dinv[n]*hWs[n]   (self-loop in fp32)

__global__ __launch_bounds__(256) void k_gemm_dual(const float* __restrict__ Xin,
                                                   const unsigned short* __restrict__ gsum,
                                                   const float* __restrict__ Wc, const float* __restrict__ Wr,
                                                   const float* __restrict__ cb, const float* __restrict__ rb,
                                                   const float* __restrict__ dinv,
                                                   signed char* __restrict__ hWq, float* __restrict__ scl,
                                                   float* __restrict__ agg, int mode) {
  __shared__ float Xs[64 * 64];
  __shared__ float Wcs[64 * 64];
  __shared__ float Wrs[64 * 64];
  int t = threadIdx.x;
#pragma unroll
  for (int j = 0; j < 4; j++) {
    ((float4*)Wcs)[t + j * 256] = ((const float4*)Wc)[t + j * 256];
    ((float4*)Wrs)[t + j * 256] = ((const float4*)Wr)[t + j * 256];
  }
  int n0 = blockIdx.x * 64;
#pragma unroll
  for (int i = 0; i < 4; i++) {
    int idx = t + i * 256;        // float4 index in 64x64 tile (1024 total)
    int n = idx >> 4;             // 16 float4 per row
    int kg = (idx & 15) << 2;
    float4 v = make_float4(0.f, 0.f, 0.f, 0.f);
    int gn = n0 + n;
    if (gn < NN) {
      v = *(const float4*)(Xin + gn * 64 + kg);
      if (mode) {
        ushort4 g = *(const ushort4*)(gsum + gn * 64 + kg);
        float dvn = dinv[gn];
        v.x = fmaxf(v.x + dvn * bf2f(g.x), 0.f);
        v.y = fmaxf(v.y + dvn * bf2f(g.y), 0.f);
        v.z = fmaxf(v.z + dvn * bf2f(g.z), 0.f);
        v.w = fmaxf(v.w + dvn * bf2f(g.w), 0.f);
      }
    }
    int sw = ((n >> 2) & 7) << 2;  // float4-preserving bank swizzle
    *(float4*)(Xs + n * 64 + (kg ^ sw)) = v;
  }
  __syncthreads();

  int hg = (t & 15) << 2;   // h0 (4 consecutive h)
  int ng = t >> 4;          // node group (16 groups x 4 nodes)
  int nb = ng << 2;
  int swz = (ng & 7) << 2;  // rows nb..nb+3 share row>>2 == ng

  float aC[4][4] = {};
  float aR[4][4] = {};
#pragma unroll 4
  for (int k = 0; k < 64; k++) {
    float4 wc = *(const float4*)(Wcs + k * 64 + hg);
    float4 wr = *(const float4*)(Wrs + k * 64 + hg);
    int kk = k ^ swz;
#pragma unroll
    for (int i = 0; i < 4; i++) {
      float xv = Xs[(nb + i) * 64 + kk];
      aC[i][0] += xv * wc.x; aC[i][1] += xv * wc.y; aC[i][2] += xv * wc.z; aC[i][3] += xv * wc.w;
      aR[i][0] += xv * wr.x; aR[i][1] += xv * wr.y; aR[i][2] += xv * wr.z; aR[i][3] += xv * wr.w;
    }
  }

  float4 cbv = *(const float4*)(cb + hg);
  float4 rbv = *(const float4*)(rb + hg);
#pragma unroll
  for (int i = 0; i < 4; i++) {
    int n = n0 + nb + i;
    if (n < NN) {  // uniform across the 16-lane row group (same n) -> shuffles safe
      float dv = dinv[n];
      float4 hv;
      hv.x = dv * aC[i][0]; hv.y = dv * aC[i][1]; hv.z = dv * aC[i][2]; hv.w = dv * aC[i][3];
      // row max over the 16 threads holding this node's 64 h values
      float m = fmaxf(fmaxf(fabsf(hv.x), fabsf(hv.y)), fmaxf(fabsf(hv.z), fabsf(hv.w)));
      m = fmaxf(m, __shfl_xor(m, 1, 64));
      m = fmaxf(m, __shfl_xor(m, 2, 64));
      m = fmaxf(m, __shfl_xor(m, 4, 64));
      m = fmaxf(m, __shfl_xor(m, 8, 64));
      float inv = (m > 0.f) ? 127.f / m : 0.f;
      int qx = (int)rintf(hv.x * inv);
      int qy = (int)rintf(hv.y * inv);
      int qz = (int)rintf(hv.z * inv);
      int qw = (int)rintf(hv.w * inv);
      int packed = (qx & 255) | ((qy & 255) << 8) | ((qz & 255) << 16) | (qw << 24);
      *(int*)(hWq + (size_t)n * 64 + hg) = packed;
      if ((t & 15) == 0) scl[n] = m * (1.f / 127.f);
      float4 av;
      av.x = aR[i][0] + rbv.x + cbv.x + dv * hv.x;
      av.y = aR[i][1] + rbv.y + cbv.y + dv * hv.y;
      av.z = aR[i][2] + rbv.z + cbv.z + dv * hv.z;
      av.w = aR[i][3] + rbv.w + cbv.w + dv * hv.w;
      *(float4*)(agg + n * 64 + hg) = av;
    }
  }
}

// ---------------- CSR gather: gsum[n] = bf16( sum_e scl[s]*q8[s] ) ----------------
// One 64-lane wave per dst node. PURE VECTOR path (R11 post-mortem: readfirstlane +
// s_load serialized on lgkmcnt with the shuffles): indices stay in VGPRs; scl[s] is a
// same-address vector load -> 1 broadcast txn, L2-resident; 16 int8 row loads (64 B,
// 2 rows/line) stay independent and in flight. Last layer skips gsum, fuses decode.

__global__ __launch_bounds__(256) void k_gather(const int* __restrict__ rowst, const int* __restrict__ rowen,
                                                const int* __restrict__ cols,
                                                const signed char* __restrict__ hWq,
                                                const float* __restrict__ scl,
                                                unsigned short* __restrict__ gsum,
                                                const float* __restrict__ agg, const float* __restrict__ dinv,
                                                const float* __restrict__ decW, float* __restrict__ Xo,
                                                int last) {
  int lane = threadIdx.x & 63;
  int n = __builtin_amdgcn_readfirstlane(blockIdx.x * 4 + (threadIdx.x >> 6));
  int st = rowst[n];
  int en = rowen[n];
  int deg = en - st;
  float acc = 0.f;
  for (int base = 0; base < deg; base += 64) {
    int cnt = deg - base;
    if (cnt > 64) cnt = 64;
    int li = lane < cnt ? lane : cnt - 1;
    int colv = cols[st + base + li];  // one coalesced row-load of up to 64 indices
    for (int j = 0; j < cnt; j += 16) {
      int i0 = j + 0, i1 = j + 1, i2 = j + 2, i3 = j + 3;
      int i4 = j + 4, i5 = j + 5, i6 = j + 6, i7 = j + 7;
      int i8 = j + 8, i9 = j + 9, iA = j + 10, iB = j + 11;
      int iC = j + 12, iD = j + 13, iE = j + 14, iF = j + 15;
      int s0 = __shfl(colv, i0, 64);
      int s1 = __shfl(colv, i1 < cnt ? i1 : j, 64);
      int s2 = __shfl(colv, i2 < cnt ? i2 : j, 64);
      int s3 = __shfl(colv, i3 < cnt ? i3 : j, 64);
      int s4 = __shfl(colv, i4 < cnt ? i4 : j, 64);
      int s5 = __shfl(colv, i5 < cnt ? i5 : j, 64);
      int s6 = __shfl(colv, i6 < cnt ? i6 : j, 64);
      int s7 = __shfl(colv, i7 < cnt ? i7 : j, 64);
      int s8 = __shfl(colv, i8 < cnt ? i8 : j, 64);
      int s9 = __shfl(colv, i9 < cnt ? i9 : j, 64);
      int sA = __shfl(colv, iA < cnt ? iA : j, 64);
      int sB = __shfl(colv, iB < cnt ? iB : j, 64);
      int sC = __shfl(colv, iC < cnt ? iC : j, 64);
      int sD = __shfl(colv, iD < cnt ? iD : j, 64);
      int sE = __shfl(colv, iE < cnt ? iE : j, 64);
      int sF = __shfl(colv, iF < cnt ? iF : j, 64);
      // independent vector loads: 16 x 64 B rows + 16 broadcast scale words
      float v0 = (float)hWq[(size_t)s0 * 64 + lane];
      float v1 = (float)hWq[(size_t)s1 * 64 + lane];
      float v2 = (float)hWq[(size_t)s2 * 64 + lane];
      float v3 = (float)hWq[(size_t)s3 * 64 + lane];
      float v4 = (float)hWq[(size_t)s4 * 64 + lane];
      float v5 = (float)hWq[(size_t)s5 * 64 + lane];
      float v6 = (float)hWq[(size_t)s6 * 64 + lane];
      float v7 = (float)hWq[(size_t)s7 * 64 + lane];
      float v8 = (float)hWq[(size_t)s8 * 64 + lane];
      float v9 = (float)hWq[(size_t)s9 * 64 + lane];
      float vA = (float)hWq[(size_t)sA * 64 + lane];
      float vB = (float)hWq[(size_t)sB * 64 + lane];
      float vC = (float)hWq[(size_t)sC * 64 + lane];
      float vD = (float)hWq[(size_t)sD * 64 + lane];
      float vE = (float)hWq[(size_t)sE * 64 + lane];
      float vF = (float)hWq[(size_t)sF * 64 + lane];
      float w0 = scl[s0], w1 = scl[s1], w2 = scl[s2], w3 = scl[s3];
      float w4 = scl[s4], w5 = scl[s5], w6 = scl[s6], w7 = scl[s7];
      float w8 = scl[s8], w9 = scl[s9], wA = scl[sA], wB = scl[sB];
      float wC = scl[sC], wD = scl[sD], wE = scl[sE], wF = scl[sF];
      acc += w0 * v0;
      acc += (i1 < cnt) ? w1 * v1 : 0.f;
      acc += (i2 < cnt) ? w2 * v2 : 0.f;
      acc += (i3 < cnt) ? w3 * v3 : 0.f;
      acc += (i4 < cnt) ? w4 * v4 : 0.f;
      acc += (i5 < cnt) ? w5 * v5 : 0.f;
      acc += (i6 < cnt) ? w6 * v6 : 0.f;
      acc += (i7 < cnt) ? w7 * v7 : 0.f;
      acc += (i8 < cnt) ? w8 * v8 : 0.f;
      acc += (i9 < cnt) ? w9 * v9 : 0.f;
      acc += (iA < cnt) ? wA * vA : 0.f;
      acc += (iB < cnt) ? wB * vB : 0.f;
      acc += (iC < cnt) ? wC * vC : 0.f;
      acc += (iD < cnt) ? wD * vD : 0.f;
      acc += (iE < cnt) ? wE * vE : 0.f;
      acc += (iF < cnt) ? wF * vF : 0.f;
    }
  }
  if (!last) {
    gsum[n * 64 + lane] = f2bf(acc);
  } else {
    float xf = agg[n * 64 + lane] + dinv[n] * acc;  // X_final pre-relu (fp32 acc)
    float v = fmaxf(xf, 0.f) * decW[lane];
#pragma unroll
    for (int off = 32; off > 0; off >>= 1) v += __shfl_down(v, off, 64);
    if (lane == 0) Xo[n] = v;
  }
}

// ---------------- graph pooling: out[g] = sum Xo[gptr[g]:gptr[g+1]] + cnt*decb ----------------

__global__ __launch_bounds__(256) void k_pool(const float* __restrict__ Xo, const int* __restrict__ gptr,
                                              const float* __restrict__ decb, float* __restrict__ out) {
  __shared__ float part[4];
  int g = blockIdx.x;
  int t = threadIdx.x;
  int st = gptr[g], en = gptr[g + 1];
  float v = 0.f;
  for (int i = st + t; i < en; i += 256) v += Xo[i];
#pragma unroll
  for (int off = 32; off > 0; off >>= 1) v += __shfl_down(v, off, 64);
  if ((t & 63) == 0) part[t >> 6] = v;
  __syncthreads();
  if (t == 0) out[g] = part[0] + part[1] + part[2] + part[3] + (float)(en - st) * decb[0];
}

// ---------------- launch ----------------

extern "C" void kernel_launch(void* const* d_in, const int* in_sizes, int n_in,
                              void* d_out, int out_size, void* d_ws, size_t ws_size,
                              hipStream_t stream) {
  (void)in_sizes; (void)n_in; (void)out_size; (void)ws_size;
  const float* x     = (const float*)d_in[0];
  const float* pos   = (const float*)d_in[1];
  const int*   ei    = (const int*)d_in[2];
  const int*   batch = (const int*)d_in[3];
  const float* encW  = (const float*)d_in[4];
  const float* encb  = (const float*)d_in[5];
  const float* convW = (const float*)d_in[6];
  const float* convb = (const float*)d_in[7];
  const float* resW  = (const float*)d_in[8];
  const float* resb  = (const float*)d_in[9];
  const float* decW  = (const float*)d_in[10];
  const float* decb  = (const float*)d_in[11];
  float* out = (float*)d_out;

  const int* src = ei;       // edge_index[0]
  const int* dst = ei + NE;  // edge_index[1]

  // workspace layout (4-byte elems)
  float*          ws     = (float*)d_ws;
  float*          dinv   = ws;                          // [NPAD]
  int*            rowst  = (int*)(ws + NPAD);           // [NPAD]
  int*            rowen  = (int*)(ws + 2 * NPAD);       // [NPAD]
  int*            bcur   = (int*)(ws + 3 * NPAD);       // [1024]
  int*            gptr   = bcur + 1024;                 // [NG+1]
  float*          Xo     = (float*)(gptr + 512);        // [NPAD]
  float*          scl    = Xo + NPAD;                   // [NPAD] int8 row scales
  int*            colp   = (int*)(scl + NPAD);          // [NBKT*CAP] packed (src<<6)|dstLow
  int*            cols   = colp + NBKT * CAP;           // [NBKT*CAP] sorted src
  signed char*    hWq    = (signed char*)(cols + NBKT * CAP);           // [NPAD*64] int8
  unsigned short* gsum   = (unsigned short*)(hWq + (size_t)NPAD * 64);  // [NPAD*64] bf16
  float*          bufA   = (float*)(gsum + (size_t)NPAD * 64);          // [NN*NH]
  float*          bufB   = bufA + NN * NH;

  hipMemsetAsync(bcur, 0, 1024 * sizeof(int), stream);

  k_bin<<<(NE + 8191) / 8192, 256, 0, stream>>>(src, dst, bcur, colp);
  k_csr<<<NBKT, 256, 0, stream>>>(bcur, colp, cols, dinv, rowst, rowen, batch, gptr);

  k_encoder<<<(NN + 3) / 4, 256, 0, stream>>>(x, pos, encW, encb, bufA);

  float* aggIn = bufA;   // X0 for l=0; thereafter agg_{l-1}
  float* aggOut = bufB;
  for (int l = 0; l < 5; l++) {
    int last = (l == 4) ? 1 : 0;
    k_gemm_dual<<<NBKT, 256, 0, stream>>>(aggIn, gsum, convW, resW, convb, resb, dinv,
                                          hWq, scl, aggOut, l > 0 ? 1 : 0);
    k_gather<<<NN / 4, 256, 0, stream>>>(rowst, rowen, cols, hWq, scl, gsum,
                                         aggOut, dinv, decW, Xo, last);
    float* tmp = aggIn; aggIn = aggOut; aggOut = tmp;
  }
  k_pool<<<NG, 256, 0, stream>>>(Xo, gptr, decb, out);
}

// Round 13
// 328.653 us; speedup vs baseline: 1.2469x; 1.0991x over previous
//
#include <hip/hip_runtime.h>

#define NN 50000
#define NE 800000
#define NH 64
#define NG 500
#define NPAD 50176   // 196*256
#define NBKT 782     // ceil(NN/64) 64-node buckets
#define CAP 1536     // padded bucket capacity (max bucket deg ~1130; 4.5+ sigma margin)

// fp32 -> bf16 round-to-nearest-even
__device__ __forceinline__ unsigned short f2bf(float f) {
  unsigned x = __float_as_uint(f);
  unsigned r = ((x >> 16) & 1u) + 0x7fffu;
  return (unsigned short)((x + r) >> 16);
}
__device__ __forceinline__ float bf2f(unsigned short u) {
  return __uint_as_float(((unsigned)u) << 16);
}

// ---------------- binning into padded buckets: colp[b*CAP + r] ----------------

__global__ __launch_bounds__(256) void k_bin(const int* __restrict__ src, const int* __restrict__ dst,
                                             int* __restrict__ bcur, int* __restrict__ colp) {
  __shared__ int hist[NBKT];
  __shared__ int gbase[NBKT];
  int t = threadIdx.x;
  for (int b = t; b < NBKT; b += 256) hist[b] = 0;
  __syncthreads();
  int e0 = blockIdx.x * 8192;
#pragma unroll
  for (int i = 0; i < 32; i++) {
    int e = e0 + i * 256 + t;
    if (e < NE) atomicAdd(&hist[dst[e] >> 6], 1);
  }
  __syncthreads();
  for (int b = t; b < NBKT; b += 256) {
    int c = hist[b];
    gbase[b] = c ? atomicAdd(&bcur[b], c) : 0;
    hist[b] = 0;  // reuse as rank counter
  }
  __syncthreads();
#pragma unroll
  for (int i = 0; i < 32; i++) {
    int e = e0 + i * 256 + t;
    if (e < NE) {
      int s = src[e], d = dst[e];
      int b = d >> 6;
      int r = atomicAdd(&hist[b], 1);
      colp[b * CAP + gbase[b] + r] = (s << 6) | (d & 63);
    }
  }
}

// ---------------- bucket-local sort to padded CSR + dinv/rowst/rowen (+ gptr folded) ----------------

__global__ __launch_bounds__(256) void k_csr(const int* __restrict__ bcur, const int* __restrict__ colp,
                                             int* __restrict__ cols, float* __restrict__ dinv,
                                             int* __restrict__ rowst, int* __restrict__ rowen,
                                             const int* __restrict__ batch, int* __restrict__ gptr) {
  __shared__ int hist[64];
  __shared__ int excl[65];
  int t = threadIdx.x;
  int b = blockIdx.x;

  // folded gptr: graph segment pointers from sorted batch (independent work)
  int tid = b * 256 + t;
  if (tid < NN) {
    int bi = batch[tid];
    int bp = (tid > 0) ? batch[tid - 1] : -1;
    for (int g = bp + 1; g <= bi; g++) gptr[g] = tid;
    if (tid == NN - 1) {
      for (int g = bi + 1; g <= NG; g++) gptr[g] = NN;
    }
  }

  int base = b * CAP;
  int cnt = bcur[b];
  if (t < 64) hist[t] = 0;
  __syncthreads();
  for (int e = t; e < cnt; e += 256) atomicAdd(&hist[colp[base + e] & 63], 1);
  __syncthreads();
  if (t == 0) {
    int run = 0;
#pragma unroll
    for (int i = 0; i < 64; i++) { excl[i] = run; run += hist[i]; }
    excl[64] = run;
  }
  __syncthreads();
  if (t < 64) {
    int n = b * 64 + t;
    rowst[n] = base + excl[t];
    rowen[n] = base + excl[t + 1];
    if (n < NN) dinv[n] = rsqrtf((float)(hist[t] + 1));  // +1 self-loop
    hist[t] = 0;  // reuse as cursor
  }
  __syncthreads();
  for (int e = t; e < cnt; e += 256) {
    int w = colp[base + e];
    int d = w & 63;
    int r = atomicAdd(&hist[d], 1);
    cols[base + excl[d] + r] = w >> 6;
  }
}

// ---------------- encoder: X0 = [x|pos] @ enc_W + enc_b ----------------

__global__ __launch_bounds__(256) void k_encoder(const float* __restrict__ x, const float* __restrict__ pos,
                                                 const float* __restrict__ W, const float* __restrict__ b,
                                                 float* __restrict__ X0) {
  __shared__ float Ws[16 * 64];
  __shared__ float bs[64];
  int t = threadIdx.x;
  for (int i = t; i < 1024; i += 256) Ws[i] = W[i];
  if (t < 64) bs[t] = b[t];
  __syncthreads();
  int n = blockIdx.x * 4 + (t >> 6);
  int h = t & 63;
  if (n >= NN) return;
  float acc = bs[h];
#pragma unroll
  for (int f = 0; f < 14; f++) acc += x[n * 14 + f] * Ws[f * 64 + h];
  acc += pos[n * 2 + 0] * Ws[14 * 64 + h];
  acc += pos[n * 2 + 1] * Ws[15 * 64 + h];
  X0[n * 64 + h] = acc;
}

// ---------------- fused dual GEMM + epilogue (64-node tile, 48 KB LDS -> 3 blocks/CU) ----------------
// mode 0: X = Xin (encoder output). mode 1: X = relu(Xin + dinv[n]*bf2f(gsum[n])).
// hWbf = bf16( dinv[n] * (X @ conv_W) )   (gather sums these)
// agg  = X @ res_W + res_b + conv_b + dinv[n]*hWs[n]   (self-loop in fp32)

__global__ __launch_bounds__(256) void k_gemm_dual(const float* __restrict__ Xin,
                                                   const unsigned short* __restrict__ gsum,
                                                   const float* __restrict__ Wc, const float* __restrict__ Wr,
                                                   const float* __restrict__ cb, const float* __restrict__ rb,
                                                   const float* __restrict__ dinv,
                                                   unsigned short* __restrict__ hWbf, float* __restrict__ agg,
                                                   int mode) {
  __shared__ float Xs[64 * 64];
  __shared__ float Wcs[64 * 64];
  __shared__ float Wrs[64 * 64];
  int t = threadIdx.x;
#pragma unroll
  for (int j = 0; j < 4; j++) {
    ((float4*)Wcs)[t + j * 256] = ((const float4*)Wc)[t + j * 256];
    ((float4*)Wrs)[t + j * 256] = ((const float4*)Wr)[t + j * 256];
  }
  int n0 = blockIdx.x * 64;
#pragma unroll
  for (int i = 0; i < 4; i++) {
    int idx = t + i * 256;        // float4 index in 64x64 tile (1024 total)
    int n = idx >> 4;             // 16 float4 per row
    int kg = (idx & 15) << 2;
    float4 v = make_float4(0.f, 0.f, 0.f, 0.f);
    int gn = n0 + n;
    if (gn < NN) {
      v = *(const float4*)(Xin + gn * 64 + kg);
      if (mode) {
        ushort4 g = *(const ushort4*)(gsum + gn * 64 + kg);
        float dvn = dinv[gn];
        v.x = fmaxf(v.x + dvn * bf2f(g.x), 0.f);
        v.y = fmaxf(v.y + dvn * bf2f(g.y), 0.f);
        v.z = fmaxf(v.z + dvn * bf2f(g.z), 0.f);
        v.w = fmaxf(v.w + dvn * bf2f(g.w), 0.f);
      }
    }
    int sw = ((n >> 2) & 7) << 2;  // float4-preserving bank swizzle
    *(float4*)(Xs + n * 64 + (kg ^ sw)) = v;
  }
  __syncthreads();

  int hg = (t & 15) << 2;   // h0 (4 consecutive h)
  int ng = t >> 4;          // node group (16 groups x 4 nodes)
  int nb = ng << 2;
  int swz = (ng & 7) << 2;  // rows nb..nb+3 share row>>2 == ng

  float aC[4][4] = {};
  float aR[4][4] = {};
#pragma unroll 4
  for (int k = 0; k < 64; k++) {
    float4 wc = *(const float4*)(Wcs + k * 64 + hg);
    float4 wr = *(const float4*)(Wrs + k * 64 + hg);
    int kk = k ^ swz;
#pragma unroll
    for (int i = 0; i < 4; i++) {
      float xv = Xs[(nb + i) * 64 + kk];
      aC[i][0] += xv * wc.x; aC[i][1] += xv * wc.y; aC[i][2] += xv * wc.z; aC[i][3] += xv * wc.w;
      aR[i][0] += xv * wr.x; aR[i][1] += xv * wr.y; aR[i][2] += xv * wr.z; aR[i][3] += xv * wr.w;
    }
  }

  float4 cbv = *(const float4*)(cb + hg);
  float4 rbv = *(const float4*)(rb + hg);
#pragma unroll
  for (int i = 0; i < 4; i++) {
    int n = n0 + nb + i;
    if (n < NN) {
      float dv = dinv[n];
      float4 hv;
      hv.x = dv * aC[i][0]; hv.y = dv * aC[i][1]; hv.z = dv * aC[i][2]; hv.w = dv * aC[i][3];
      ushort4 hb;
      hb.x = f2bf(hv.x); hb.y = f2bf(hv.y); hb.z = f2bf(hv.z); hb.w = f2bf(hv.w);
      *(ushort4*)(hWbf + (size_t)n * 64 + hg) = hb;
      float4 av;
      av.x = aR[i][0] + rbv.x + cbv.x + dv * hv.x;
      av.y = aR[i][1] + rbv.y + cbv.y + dv * hv.y;
      av.z = aR[i][2] + rbv.z + cbv.z + dv * hv.z;
      av.w = aR[i][3] + rbv.w + cbv.w + dv * hv.w;
      *(float4*)(agg + n * 64 + hg) = av;
    }
  }
}

// ---------------- CSR gather, PAIRED rows: 2 edges per load instruction ----------------
// One 64-lane wave per dst node. Lane = (p = lane>>5, h2 = lane&31): handles h = 2*h2,
// 2*h2+1 of edge-slot pair-member p. A bf16 row is 128 B = 32 lanes x 4 B, so one wave
// load covers TWO rows -> 8 load instructions per 16 edges (was 16). Same lines, same
// bytes — clean discriminator for per-instruction vs per-line cost models.
// End: combine p-halves via shfl, lanes 0..31 hold the full 64-h sum as pairs.
// Last layer reads agg once and fuses decode.

__global__ __launch_bounds__(256) void k_gather(const int* __restrict__ rowst, const int* __restrict__ rowen,
                                                const int* __restrict__ cols,
                                                const unsigned short* __restrict__ hWbf,
                                                unsigned short* __restrict__ gsum,
                                                const float* __restrict__ agg, const float* __restrict__ dinv,
                                                const float* __restrict__ decW, float* __restrict__ Xo,
                                                int last) {
  int lane = threadIdx.x & 63;
  int h2 = lane & 31;   // h-pair: h = 2*h2, 2*h2+1
  int p = lane >> 5;    // which member of each edge pair
  int n = __builtin_amdgcn_readfirstlane(blockIdx.x * 4 + (threadIdx.x >> 6));
  int st = rowst[n];
  int en = rowen[n];
  int deg = en - st;
  float a0 = 0.f, a1 = 0.f;
  for (int base = 0; base < deg; base += 64) {
    int cnt = deg - base;
    if (cnt > 64) cnt = 64;
    int li = lane < cnt ? lane : cnt - 1;
    int colv = cols[st + base + li];  // one coalesced load of up to 64 indices
    for (int j = 0; j < cnt; j += 16) {
      int e0 = j + 0 + p, e1 = j + 2 + p, e2 = j + 4 + p, e3 = j + 6 + p;
      int e4 = j + 8 + p, e5 = j + 10 + p, e6 = j + 12 + p, e7 = j + 14 + p;
      int s0 = __shfl(colv, e0 < cnt ? e0 : j, 64);
      int s1 = __shfl(colv, e1 < cnt ? e1 : j, 64);
      int s2 = __shfl(colv, e2 < cnt ? e2 : j, 64);
      int s3 = __shfl(colv, e3 < cnt ? e3 : j, 64);
      int s4 = __shfl(colv, e4 < cnt ? e4 : j, 64);
      int s5 = __shfl(colv, e5 < cnt ? e5 : j, 64);
      int s6 = __shfl(colv, e6 < cnt ? e6 : j, 64);
      int s7 = __shfl(colv, e7 < cnt ? e7 : j, 64);
      unsigned u0 = *(const unsigned*)(hWbf + (size_t)s0 * 64 + h2 * 2);
      unsigned u1 = *(const unsigned*)(hWbf + (size_t)s1 * 64 + h2 * 2);
      unsigned u2 = *(const unsigned*)(hWbf + (size_t)s2 * 64 + h2 * 2);
      unsigned u3 = *(const unsigned*)(hWbf + (size_t)s3 * 64 + h2 * 2);
      unsigned u4 = *(const unsigned*)(hWbf + (size_t)s4 * 64 + h2 * 2);
      unsigned u5 = *(const unsigned*)(hWbf + (size_t)s5 * 64 + h2 * 2);
      unsigned u6 = *(const unsigned*)(hWbf + (size_t)s6 * 64 + h2 * 2);
      unsigned u7 = *(const unsigned*)(hWbf + (size_t)s7 * 64 + h2 * 2);
      a0 += (e0 < cnt) ? bf2f((unsigned short)(u0 & 0xffff)) : 0.f;
      a1 += (e0 < cnt) ? bf2f((unsigned short)(u0 >> 16)) : 0.f;
      a0 += (e1 < cnt) ? bf2f((unsigned short)(u1 & 0xffff)) : 0.f;
      a1 += (e1 < cnt) ? bf2f((unsigned short)(u1 >> 16)) : 0.f;
      a0 += (e2 < cnt) ? bf2f((unsigned short)(u2 & 0xffff)) : 0.f;
      a1 += (e2 < cnt) ? bf2f((unsigned short)(u2 >> 16)) : 0.f;
      a0 += (e3 < cnt) ? bf2f((unsigned short)(u3 & 0xffff)) : 0.f;
      a1 += (e3 < cnt) ? bf2f((unsigned short)(u3 >> 16)) : 0.f;
      a0 += (e4 < cnt) ? bf2f((unsigned short)(u4 & 0xffff)) : 0.f;
      a1 += (e4 < cnt) ? bf2f((unsigned short)(u4 >> 16)) : 0.f;
      a0 += (e5 < cnt) ? bf2f((unsigned short)(u5 & 0xffff)) : 0.f;
      a1 += (e5 < cnt) ? bf2f((unsigned short)(u5 >> 16)) : 0.f;
      a0 += (e6 < cnt) ? bf2f((unsigned short)(u6 & 0xffff)) : 0.f;
      a1 += (e6 < cnt) ? bf2f((unsigned short)(u6 >> 16)) : 0.f;
      a0 += (e7 < cnt) ? bf2f((unsigned short)(u7 & 0xffff)) : 0.f;
      a1 += (e7 < cnt) ? bf2f((unsigned short)(u7 >> 16)) : 0.f;
    }
  }
  // combine the two pair-halves: lanes 0..31 get full sums for their h-pair
  a0 += __shfl_down(a0, 32, 64);
  a1 += __shfl_down(a1, 32, 64);
  if (!last) {
    if (lane < 32) {
      unsigned outw = (unsigned)f2bf(a0) | ((unsigned)f2bf(a1) << 16);
      *(unsigned*)(gsum + (size_t)n * 64 + h2 * 2) = outw;
    }
  } else {
    float dv = dinv[n];
    float2 ag = *(const float2*)(agg + (size_t)n * 64 + h2 * 2);  // valid addr for all lanes
    float xf0 = ag.x + dv * a0;
    float xf1 = ag.y + dv * a1;
    float v = fmaxf(xf0, 0.f) * decW[h2 * 2] + fmaxf(xf1, 0.f) * decW[h2 * 2 + 1];
    v = (lane < 32) ? v : 0.f;  // upper half holds stale partials -> zero them
#pragma unroll
    for (int off = 32; off > 0; off >>= 1) v += __shfl_down(v, off, 64);
    if (lane == 0) Xo[n] = v;
  }
}

// ---------------- graph pooling: out[g] = sum Xo[gptr[g]:gptr[g+1]] + cnt*decb ----------------

__global__ __launch_bounds__(256) void k_pool(const float* __restrict__ Xo, const int* __restrict__ gptr,
                                              const float* __restrict__ decb, float* __restrict__ out) {
  __shared__ float part[4];
  int g = blockIdx.x;
  int t = threadIdx.x;
  int st = gptr[g], en = gptr[g + 1];
  float v = 0.f;
  for (int i = st + t; i < en; i += 256) v += Xo[i];
#pragma unroll
  for (int off = 32; off > 0; off >>= 1) v += __shfl_down(v, off, 64);
  if ((t & 63) == 0) part[t >> 6] = v;
  __syncthreads();
  if (t == 0) out[g] = part[0] + part[1] + part[2] + part[3] + (float)(en - st) * decb[0];
}

// ---------------- launch ----------------

extern "C" void kernel_launch(void* const* d_in, const int* in_sizes, int n_in,
                              void* d_out, int out_size, void* d_ws, size_t ws_size,
                              hipStream_t stream) {
  (void)in_sizes; (void)n_in; (void)out_size; (void)ws_size;
  const float* x     = (const float*)d_in[0];
  const float* pos   = (const float*)d_in[1];
  const int*   ei    = (const int*)d_in[2];
  const int*   batch = (const int*)d_in[3];
  const float* encW  = (const float*)d_in[4];
  const float* encb  = (const float*)d_in[5];
  const float* convW = (const float*)d_in[6];
  const float* convb = (const float*)d_in[7];
  const float* resW  = (const float*)d_in[8];
  const float* resb  = (const float*)d_in[9];
  const float* decW  = (const float*)d_in[10];
  const float* decb  = (const float*)d_in[11];
  float* out = (float*)d_out;

  const int* src = ei;       // edge_index[0]
  const int* dst = ei + NE;  // edge_index[1]

  // workspace layout (4-byte elems)
  float*          ws     = (float*)d_ws;
  float*          dinv   = ws;                          // [NPAD]
  int*            rowst  = (int*)(ws + NPAD);           // [NPAD]
  int*            rowen  = (int*)(ws + 2 * NPAD);       // [NPAD]
  int*            bcur   = (int*)(ws + 3 * NPAD);       // [1024]
  int*            gptr   = bcur + 1024;                 // [NG+1]
  float*          Xo     = (float*)(gptr + 512);        // [NPAD]
  int*            colp   = (int*)(Xo + NPAD);           // [NBKT*CAP] packed (src<<6)|dstLow
  int*            cols   = colp + NBKT * CAP;           // [NBKT*CAP] sorted src
  unsigned short* hWbf   = (unsigned short*)(cols + NBKT * CAP);        // [NPAD*64] bf16
  unsigned short* gsum   = hWbf + (size_t)NPAD * 64;                    // [NPAD*64] bf16
  float*          bufA   = (float*)(gsum + (size_t)NPAD * 64);          // [NN*NH]
  float*          bufB   = bufA + NN * NH;

  hipMemsetAsync(bcur, 0, 1024 * sizeof(int), stream);

  k_bin<<<(NE + 8191) / 8192, 256, 0, stream>>>(src, dst, bcur, colp);
  k_csr<<<NBKT, 256, 0, stream>>>(bcur, colp, cols, dinv, rowst, rowen, batch, gptr);

  k_encoder<<<(NN + 3) / 4, 256, 0, stream>>>(x, pos, encW, encb, bufA);

  float* aggIn = bufA;   // X0 for l=0; thereafter agg_{l-1}
  float* aggOut = bufB;
  for (int l = 0; l < 5; l++) {
    int last = (l == 4) ? 1 : 0;
    k_gemm_dual<<<NBKT, 256, 0, stream>>>(aggIn, gsum, convW, resW, convb, resb, dinv,
                                          hWbf, aggOut, l > 0 ? 1 : 0);
    k_gather<<<NN / 4, 256, 0, stream>>>(rowst, rowen, cols, hWbf, gsum,
                                         aggOut, dinv, decW, Xo, last);
    float* tmp = aggIn; aggIn = aggOut; aggOut = tmp;
  }
  k_pool<<<NG, 256, 0, stream>>>(Xo, gptr, decb, out);
}